// Round 7
// baseline (1173.607 us; speedup 1.0000x reference)
//
#include <hip/hip_runtime.h>

// SimpleARRNN: GRU encoder (len<=512) + AR decoder (257 outputs). B=512, I=64, H=100, O=64. fp32.
// Fused affine input paths: W_c = W_ih@W_embed [300x64], b_c = W_ih@b_embed + b_ih
//                           W_d = W_c@W_proj   [300x100], b_d = W_c@b_proj + b_c
// rnn15 (R15): R8 trunk + 8-LANE column split (R7->R8's proven lever, extended 4->8).
// Campaign summary: R9 stagger null, R10-13 gate-in-quad negative, R14 barrier hygiene
// null -> only per-lane-LDS-byte reduction ever won (R7->R8 -12%). R15 halves it again:
//  - lane l8=tid&7 owns h-cols [13*l8,13*l8+12] (pad 100->104 w/ zero cols) and
//    ctx-cols [8*l8, 8*l8+7]: hv = 3 b128 + 1 b32 (52 B), cv = 2 b128 (32 B) per elem.
//  - reduce stays quad-DPP only (2 stages): group's quad0 = cols low half, quad1 = high
//    half -> SPLIT accumulators sdotA (lane 0) / sdotB (lane 4); gate/out add A+B
//    (cheap phase). No ds_swizzle 3rd stage (would re-consume the LDS pipe).
//  - contiguous row regions: group g8 owns rows [start,start+cnt), cnt=11 (g8<24) /10,
//    region stride 12 (16B-aligned). Lane 0/4 buffer results and write b128 x2+b64+b32
//    (write instr count stays at R8 level). slot(row) precomputed for gate/out readers.
//  - h layout: 8 chunks of 13(+pad), chunk c at float off 16c+4(c>>1): the 8 lanes'
//    b128 reads cover all 32 banks exactly once (conflict-free, 16B aligned).
//  - decoder body branch-free (all 664 rows are h-dots incl. proj).
// Everything else R8-verbatim: 2x __syncthreads/step, roles (gate<200, out 256..383,
// prefetch 384..415), biases in LDS, length-sorted long+short pairing, 256x512,
// waves_per_eu(2,2).

#define B_  512
#define LC_ 512
#define I_  64
#define H_  100
#define O_  64
#define T_  256
#define H3  300

// ws float offsets
#define WS_WC   0        // [300][64]
#define WS_BC   19200    // [300]
#define WS_WD   19500    // [300][100]
#define WS_BD   49500    // [300]
#define WS_PERM 49800    // int[512]

typedef float v2f __attribute__((ext_vector_type(2)));

__global__ __launch_bounds__(64) void prep1(const float* __restrict__ Wih,
                                            const float* __restrict__ bih,
                                            const float* __restrict__ Wemb,
                                            const float* __restrict__ bemb,
                                            float* __restrict__ ws) {
    int j = blockIdx.x;   // 0..299
    int i = threadIdx.x;  // 0..63
    float acc = 0.f;
    for (int k = 0; k < H_; ++k) acc += Wih[j * H_ + k] * Wemb[k * I_ + i];
    ws[WS_WC + j * I_ + i] = acc;
    if (i == 0) {
        float b = bih[j];
        for (int k = 0; k < H_; ++k) b += Wih[j * H_ + k] * bemb[k];
        ws[WS_BC + j] = b;
    }
}

__global__ __launch_bounds__(128) void prep2(const float* __restrict__ Wproj,
                                             const float* __restrict__ bproj,
                                             float* __restrict__ ws) {
    int j = blockIdx.x;   // 0..299
    int u = threadIdx.x;
    const float* Wc = ws + WS_WC;
    if (u < H_) {
        float acc = 0.f;
        for (int o = 0; o < O_; ++o) acc += Wc[j * I_ + o] * Wproj[o * H_ + u];
        ws[WS_WD + j * H_ + u] = acc;
    }
    if (u == 0) {
        float b = ws[WS_BC + j];
        for (int o = 0; o < O_; ++o) b += Wc[j * I_ + o] * bproj[o];
        ws[WS_BD + j] = b;
    }
}

// rank elements by length descending -> perm (longest first)
__global__ __launch_bounds__(512) void sortk(const int* __restrict__ lens,
                                             int* __restrict__ perm) {
    __shared__ int sl[B_];
    int tid = threadIdx.x;
    sl[tid] = lens[tid];
    __syncthreads();
    int li = sl[tid];
    int rank = 0;
    for (int j = 0; j < B_; ++j) {
        int lj = sl[j];
        rank += (lj > li) || (lj == li && j < tid);
    }
    perm[rank] = tid;
}

__device__ __forceinline__ float sigm_(float x) { return 1.f / (1.f + __expf(-x)); }
__device__ __forceinline__ float tanh_(float x) {
    float t = __expf(-2.f * fabsf(x));
    float r = (1.f - t) / (1.f + t);
    return (x >= 0.f) ? r : -r;
}

template <int CTRL>
__device__ __forceinline__ float dppmov_(float x) {
    return __int_as_float(
        __builtin_amdgcn_mov_dpp(__float_as_int(x), CTRL, 0xF, 0xF, true));
}
// reduce across the 4 lanes of a quad; all 4 lanes end with the quad sum
__device__ __forceinline__ float red4_(float a) {
    a += dppmov_<0xB1>(a);    // quad_perm [1,0,3,2] = xor1 (involution, verified R5/R7)
    a += dppmov_<0x4E>(a);    // quad_perm [2,3,0,1] = xor2
    return a;
}

// 13-col h-row dot slice: 6 v2f + tail, quad reduce -> half-row sum (A: quad0, B: quad1)
__device__ __forceinline__ float dotH8_(const v2f* __restrict__ w, float wt,
                                        const v2f* __restrict__ hv, float h12) {
    v2f a = {0.f, 0.f};
    #pragma unroll
    for (int j = 0; j < 6; ++j) a = w[j] * hv[j] + a;   // v_pk_fma_f32
    return red4_(fmaf(wt, h12, a.x + a.y));
}
// 8-col ctx-row dot slice: 4 v2f, quad reduce
__device__ __forceinline__ float dotC8_(const v2f* __restrict__ w,
                                        const v2f* __restrict__ cv) {
    v2f a = {0.f, 0.f};
    #pragma unroll
    for (int j = 0; j < 4; ++j) a = w[j] * cv[j] + a;
    return red4_(a.x + a.y);
}

// row -> sdot slot (groups 0..23 own 11 rows, 24..63 own 10; region stride 12)
__device__ __forceinline__ int slotOf_(int r) {
    return (r < 264) ? 12 * (r / 11) + (r % 11)
                     : 12 * (24 + (r - 264) / 10) + ((r - 264) % 10);
}

// predicated 13-col slice load (lane 7: cols 91..99 valid, rest zero; never deref OOB)
__device__ __forceinline__ void loadH13_(const float* __restrict__ p, int c0,
                                         v2f* __restrict__ w, float& wt) {
    #pragma unroll
    for (int j = 0; j < 6; ++j) {
        float a = (c0 + 2 * j     < H_) ? p[2 * j]     : 0.f;
        float b = (c0 + 2 * j + 1 < H_) ? p[2 * j + 1] : 0.f;
        w[j] = v2f{a, b};
    }
    wt = (c0 + 12 < H_) ? p[12] : 0.f;
}

__global__ __attribute__((amdgpu_flat_work_group_size(512, 512)))
__attribute__((amdgpu_waves_per_eu(2, 2)))
void rnn15(const float* __restrict__ ctx, const int* __restrict__ lens,
           const float* __restrict__ Whh, const float* __restrict__ bhh,
           const float* __restrict__ Wproj, const float* __restrict__ bproj,
           const float* __restrict__ ws, float* __restrict__ out) {

    const int tid = threadIdx.x;
    const int l8  = tid & 7;          // owns h-cols 13*l8.., ctx-cols 8*l8..
    const int g8  = tid >> 3;         // group 0..63

    const int* perm = (const int*)(ws + WS_PERM);
    const int e0 = perm[blockIdx.x];         // long element
    const int e1 = perm[511 - blockIdx.x];   // short element
    const int len0 = lens[e0], len1 = lens[e1];

    __shared__ __align__(16) float sh[2][140];       // h: 8 chunks, chunk c at 16c+4(c>>1)
    __shared__ __align__(16) float sctx[2][64];
    __shared__ __align__(16) float sd2[2][2][768];   // [half A/B][elem][slot]
    __shared__ float sbh[H3], sbx[H3];

    // ---- row region: group g8 owns rows [start, start+cnt) ----
    const int cnt   = (g8 < 24) ? 11 : 10;            // cnt=11 <=> tid<192 (wave-uniform)
    const int start = (g8 < 24) ? 11 * g8 : 264 + 10 * (g8 - 24);
    int nH = 300 - start; nH = nH < 0 ? 0 : (nH > 11 ? 11 : nH);   // enc: rows [0,nH) h-dots
    int nC = 600 - start; nC = nC < 0 ? 0 : (nC > 11 ? 11 : nC);   // enc: [nH,nC) ctx-dots

    // ---- register-resident weight slices (13-col h / 8-col ctx), per owned row ----
    v2f   wS[11][6];
    float w1v[11];
    const int c0 = 13 * l8;
    #pragma unroll
    for (int i = 0; i < 11; ++i) {
        if (i < cnt) {
            int row = start + i;
            if (row < 300) {
                loadH13_(Whh + row * H_ + c0, c0, wS[i], w1v[i]);
            } else if (row < 600) {
                const float* p = ws + WS_WC + (row - 300) * I_ + 8 * l8;
                #pragma unroll
                for (int j = 0; j < 4; ++j) wS[i][j] = v2f{p[2 * j], p[2 * j + 1]};
            }
            // rows >= 600 (proj): loaded at the enc->dec switch
        }
    }

    // ---- roles (R8 layout) ----
    const int ge = (tid >= 100);                 // gate threads: tid<200
    const int gi = tid - (ge ? 100 : 0);
    const int gch = gi / 13;
    const int hG = 16 * gch + 4 * (gch >> 1) + (gi % 13);   // h write slot
    const int sG0 = slotOf_(gi),       sG1 = slotOf_(gi + 100), sG2 = slotOf_(gi + 200);
    const int sG3 = slotOf_(gi + 300), sG4 = slotOf_(gi + 400), sG5 = slotOf_(gi + 500);
    const int lenG = ge ? len1 : len0;
    float hreg = 0.f;

    const int oe = (tid >> 6) & 1;               // out threads: tid in [256,384)
    const int oo = tid & 63;
    const int spr = slotOf_(600 + oo);
    float* oute = out + (size_t)(oe ? e1 : e0) * (T_ + 1) * O_;
    float bpr = 0.f;
    if (tid >= 256 && tid < 384) bpr = bproj[oo];

    const int pe = (tid >> 4) & 1;               // prefetch threads: tid in [384,416)
    const int pi = tid & 15;
    const float4* pctx = (const float4*)(ctx + (size_t)(pe ? e1 : e0) * LC_ * I_);
    const int lenP = pe ? len1 : len0;

    // ---- init ----
    if (tid < 280) ((float*)sh)[tid] = 0.f;      // zeros include pad cols (stay 0 forever)
    if (tid < H3) { sbh[tid] = bhh[tid]; sbx[tid] = (ws + WS_BC)[tid]; }
    if (tid >= 384 && tid < 416) *(float4*)&sctx[pe][4 * pi] = pctx[pi];   // t=0
    __syncthreads();

    // ---- loaders ----
    const int hO = 16 * l8 + 4 * (l8 >> 1);      // own h chunk base (16B aligned)
    auto loadHv = [&](int e, v2f* hv, float& h12) {
        const float* hb = sh[e];
        float4 f0 = *(const float4*)(hb + hO);
        float4 f1 = *(const float4*)(hb + hO + 4);
        float4 f2 = *(const float4*)(hb + hO + 8);
        hv[0] = v2f{f0.x, f0.y}; hv[1] = v2f{f0.z, f0.w};
        hv[2] = v2f{f1.x, f1.y}; hv[3] = v2f{f1.z, f1.w};
        hv[4] = v2f{f2.x, f2.y}; hv[5] = v2f{f2.z, f2.w};
        h12 = hb[hO + 12];
    };
    auto loadCv = [&](int e, v2f* cv) {
        const float* cb = sctx[e] + 8 * l8;
        float4 f0 = *(const float4*)(cb);
        float4 f1 = *(const float4*)(cb + 4);
        cv[0] = v2f{f0.x, f0.y}; cv[1] = v2f{f0.z, f0.w};
        cv[2] = v2f{f1.x, f1.y}; cv[3] = v2f{f1.z, f1.w};
    };

    // ================ encoder: t = 0 .. len0-1 (len0 >= len1) ================
    for (int t = 0; t < len0; ++t) {
        float4 pf;
        const bool hp = (tid >= 384 && tid < 416) && (t + 1 < lenP);
        if (hp) pf = pctx[(t + 1) * 16 + pi];

        #pragma unroll
        for (int e = 0; e < 2; ++e) {
            if (e == 0 || t < len1) {       // block-uniform skip of finished element
                v2f hv[6]; float h12; v2f cv[4];
                loadHv(e, hv, h12);
                loadCv(e, cv);
                #define ENC_DOT(i) ((i) < nH ? dotH8_(wS[i], w1v[i], hv, h12) \
                                   : ((i) < nC ? dotC8_(wS[i], cv) : 0.f))
                float rr0 = ENC_DOT(0), rr1 = ENC_DOT(1), rr2 = ENC_DOT(2);
                float rr3 = ENC_DOT(3), rr4 = ENC_DOT(4), rr5 = ENC_DOT(5);
                float rr6 = ENC_DOT(6), rr7 = ENC_DOT(7), rr8 = ENC_DOT(8);
                float rr9 = ENC_DOT(9);
                #undef ENC_DOT
                float rr10 = 0.f;
                if (tid < 192) rr10 = dotH8_(wS[10], w1v[10], hv, h12);  // rows<264: h-dot
                if ((l8 & 3) == 0) {
                    float* bp = &sd2[l8 >> 2][e][12 * g8];
                    *(float4*)(bp)     = make_float4(rr0, rr1, rr2, rr3);
                    *(float4*)(bp + 4) = make_float4(rr4, rr5, rr6, rr7);
                    *(float2*)(bp + 8) = make_float2(rr8, rr9);
                    if (tid < 192) bp[10] = rr10;
                }
            }
        }
        __syncthreads();
        if (tid < 200 && t < lenG) {
            const float* A = sd2[0][ge];
            const float* Bb = sd2[1][ge];
            float gr = A[sG0] + Bb[sG0] + sbh[gi];
            float gz = A[sG1] + Bb[sG1] + sbh[gi + 100];
            float gn = A[sG2] + Bb[sG2] + sbh[gi + 200];
            float xr = A[sG3] + Bb[sG3] + sbx[gi];
            float xz = A[sG4] + Bb[sG4] + sbx[gi + 100];
            float xn = A[sG5] + Bb[sG5] + sbx[gi + 200];
            float r = sigm_(xr + gr);
            float z = sigm_(xz + gz);
            float n = tanh_(xn + r * gn);
            hreg = (1.f - z) * n + z * hreg;
            sh[ge][hG] = hreg;
        }
        if (hp) *(float4*)&sctx[pe][4 * pi] = pf;
        __syncthreads();
    }

    // ---- switch input-path slices to decoder: rows>=300 become Wd/Wproj 13-col h-slices
    #pragma unroll
    for (int i = 0; i < 11; ++i) {
        if (i < cnt) {
            int row = start + i;
            if (row >= 300) {
                const float* p = (row < 600) ? (ws + WS_WD + (row - 300) * H_)
                                             : (Wproj + (row - 600) * H_);
                loadH13_(p + c0, c0, wS[i], w1v[i]);
            }
        }
    }
    if (tid < H3) sbx[tid] = (ws + WS_BD)[tid];
    // safe: sbx next read only after the decoder's first __syncthreads

    // ================ decoder: outputs t = 0..256 (branch-free dot body) ================
    for (int t = 0; t <= T_; ++t) {
        #pragma unroll
        for (int e = 0; e < 2; ++e) {
            v2f hv[6]; float h12;
            loadHv(e, hv, h12);
            float rr0 = dotH8_(wS[0], w1v[0], hv, h12);
            float rr1 = dotH8_(wS[1], w1v[1], hv, h12);
            float rr2 = dotH8_(wS[2], w1v[2], hv, h12);
            float rr3 = dotH8_(wS[3], w1v[3], hv, h12);
            float rr4 = dotH8_(wS[4], w1v[4], hv, h12);
            float rr5 = dotH8_(wS[5], w1v[5], hv, h12);
            float rr6 = dotH8_(wS[6], w1v[6], hv, h12);
            float rr7 = dotH8_(wS[7], w1v[7], hv, h12);
            float rr8 = dotH8_(wS[8], w1v[8], hv, h12);
            float rr9 = dotH8_(wS[9], w1v[9], hv, h12);
            float rr10 = 0.f;
            if (tid < 192) rr10 = dotH8_(wS[10], w1v[10], hv, h12);
            if ((l8 & 3) == 0) {
                float* bp = &sd2[l8 >> 2][e][12 * g8];
                *(float4*)(bp)     = make_float4(rr0, rr1, rr2, rr3);
                *(float4*)(bp + 4) = make_float4(rr4, rr5, rr6, rr7);
                *(float2*)(bp + 8) = make_float2(rr8, rr9);
                if (tid < 192) bp[10] = rr10;
            }
        }
        __syncthreads();
        if (tid >= 256 && tid < 384) {
            oute[t * O_ + oo] = sd2[0][oe][spr] + sd2[1][oe][spr] + bpr;
        }
        if (t == T_) break;   // uniform
        if (tid < 200) {
            const float* A = sd2[0][ge];
            const float* Bb = sd2[1][ge];
            float gr = A[sG0] + Bb[sG0] + sbh[gi];
            float gz = A[sG1] + Bb[sG1] + sbh[gi + 100];
            float gn = A[sG2] + Bb[sG2] + sbh[gi + 200];
            float xr = A[sG3] + Bb[sG3] + sbx[gi];
            float xz = A[sG4] + Bb[sG4] + sbx[gi + 100];
            float xn = A[sG5] + Bb[sG5] + sbx[gi + 200];
            float r = sigm_(xr + gr);
            float z = sigm_(xz + gz);
            float n = tanh_(xn + r * gn);
            hreg = (1.f - z) * n + z * hreg;
            sh[ge][hG] = hreg;
        }
        __syncthreads();
    }
}

extern "C" void kernel_launch(void* const* d_in, const int* in_sizes, int n_in,
                              void* d_out, int out_size, void* d_ws, size_t ws_size,
                              hipStream_t stream) {
    (void)in_sizes; (void)n_in; (void)out_size; (void)ws_size;
    const float* ctx  = (const float*)d_in[0];
    const int*   lens = (const int*)d_in[1];
    // d_in[2] = t_steps (256, hardcoded)
    const float* Wemb = (const float*)d_in[3];
    const float* bemb = (const float*)d_in[4];
    const float* Wih  = (const float*)d_in[5];
    const float* bih  = (const float*)d_in[6];
    const float* Whh  = (const float*)d_in[7];
    const float* bhh  = (const float*)d_in[8];
    const float* Wpr  = (const float*)d_in[9];
    const float* bpr  = (const float*)d_in[10];
    float* ws  = (float*)d_ws;
    float* out = (float*)d_out;

    prep1<<<H3, 64, 0, stream>>>(Wih, bih, Wemb, bemb, ws);
    prep2<<<H3, 128, 0, stream>>>(Wpr, bpr, ws);
    sortk<<<1, 512, 0, stream>>>(lens, (int*)(ws + WS_PERM));
    rnn15<<<256, 512, 0, stream>>>(ctx, lens, Whh, bhh, Wpr, bpr, ws, out);
}

// Round 8
// 729.651 us; speedup vs baseline: 1.6085x; 1.6085x over previous
//
#include <hip/hip_runtime.h>

// SimpleARRNN: GRU encoder (len<=512) + AR decoder (257 outputs). B=512, I=64, H=100, O=64. fp32.
// Fused affine input paths: W_c = W_ih@W_embed [300x64], b_c = W_ih@b_embed + b_ih
//                           W_d = W_c@W_proj   [300x100], b_d = W_c@b_proj + b_c
// rnn8 RESTORED (champion: 728.8us harness / 784us profiled).
// Campaign record (all counter-verified, all lost to this structure):
//   R9  stagger phases            794us  (null - phase walls set time, not fill)
//   R10 gate-in-quad 1-barrier   1532us  (scratch spill: divergent weight arrays)
//   R11 +sched_barrier           1454us  (spill persisted)
//   R12 +unified weight file      840us  (spill fixed; +50% issue ate the -1 barrier)
//   R13 +hoisted loads            837us  (confirmed: latency-bound, not issue-bound)
//   R14 lgkm-only barriers        801us  (vmcnt drains were not the stall)
//   R15 8-lane col split         1243us  (+42% reduce overhead, 55M bank conflicts)
// Structural model: 66400 weight floats / 512 threads = 130/lane -> <=8 waves/CU ->
// ONE barrier domain/CU; 2 barriers/step minimal (sdot + h write->read hazards);
// LDS crossbar 128B/cy is invariant to broadcast/access-shape; 4-way col split is the
// VALU/LDS U-curve minimum. rnn8 = that optimum.
// rnn8: 2 elements/block (long+short pair, length-sorted), 256 blocks x 512 threads,
// waves_per_eu(2,2) -> 256-VGPR budget (R7-proven; 124 VGPR + AGPR overflow, no scratch).
// 4-lane row split (l=tid&3 owns cols 25l..25l+24; ctx-dots cols 16l..16l+15).
// 6 passes, slot = 128p + g (g=tid>>2):
//   decoder: 0..299 Whh | 300..599 Wd | 600..663 Wproj     -> sdot[e][slot]
//   encoder: 0..299 Whh (h-dot) | 300..599 Wc (ctx-dot)    -> sdot[e][slot]
// Reduce = DPP quad_perm xor1+xor2 (involutions, verified R5/R7); lane l==0 stores.
// h in LDS: 4 chunks of 25 at stride 28 (banks 0/28/24/20 per beat - disjoint).

#define B_  512
#define LC_ 512
#define I_  64
#define H_  100
#define O_  64
#define T_  256
#define H3  300

// ws float offsets
#define WS_WC   0        // [300][64]
#define WS_BC   19200    // [300]
#define WS_WD   19500    // [300][100]
#define WS_BD   49500    // [300]
#define WS_PERM 49800    // int[512]

typedef float v2f __attribute__((ext_vector_type(2)));

__global__ __launch_bounds__(64) void prep1(const float* __restrict__ Wih,
                                            const float* __restrict__ bih,
                                            const float* __restrict__ Wemb,
                                            const float* __restrict__ bemb,
                                            float* __restrict__ ws) {
    int j = blockIdx.x;   // 0..299
    int i = threadIdx.x;  // 0..63
    float acc = 0.f;
    for (int k = 0; k < H_; ++k) acc += Wih[j * H_ + k] * Wemb[k * I_ + i];
    ws[WS_WC + j * I_ + i] = acc;
    if (i == 0) {
        float b = bih[j];
        for (int k = 0; k < H_; ++k) b += Wih[j * H_ + k] * bemb[k];
        ws[WS_BC + j] = b;
    }
}

__global__ __launch_bounds__(128) void prep2(const float* __restrict__ Wproj,
                                             const float* __restrict__ bproj,
                                             float* __restrict__ ws) {
    int j = blockIdx.x;   // 0..299
    int u = threadIdx.x;
    const float* Wc = ws + WS_WC;
    if (u < H_) {
        float acc = 0.f;
        for (int o = 0; o < O_; ++o) acc += Wc[j * I_ + o] * Wproj[o * H_ + u];
        ws[WS_WD + j * H_ + u] = acc;
    }
    if (u == 0) {
        float b = ws[WS_BC + j];
        for (int o = 0; o < O_; ++o) b += Wc[j * I_ + o] * bproj[o];
        ws[WS_BD + j] = b;
    }
}

// rank elements by length descending -> perm (longest first)
__global__ __launch_bounds__(512) void sortk(const int* __restrict__ lens,
                                             int* __restrict__ perm) {
    __shared__ int sl[B_];
    int tid = threadIdx.x;
    sl[tid] = lens[tid];
    __syncthreads();
    int li = sl[tid];
    int rank = 0;
    for (int j = 0; j < B_; ++j) {
        int lj = sl[j];
        rank += (lj > li) || (lj == li && j < tid);
    }
    perm[rank] = tid;
}

__device__ __forceinline__ float sigm_(float x) { return 1.f / (1.f + __expf(-x)); }
__device__ __forceinline__ float tanh_(float x) {
    float t = __expf(-2.f * fabsf(x));
    float r = (1.f - t) / (1.f + t);
    return (x >= 0.f) ? r : -r;
}

template <int CTRL>
__device__ __forceinline__ float dppmov_(float x) {
    return __int_as_float(
        __builtin_amdgcn_mov_dpp(__float_as_int(x), CTRL, 0xF, 0xF, true));
}
// reduce across the 4 lanes of a quad (row group); all 4 lanes end with the sum
__device__ __forceinline__ float red4_(float a) {
    a += dppmov_<0xB1>(a);    // quad_perm [1,0,3,2] = xor1 (involution, verified R5/R7)
    a += dppmov_<0x4E>(a);    // quad_perm [2,3,0,1] = xor2
    return a;
}

// h-row dot: 12 v2f pairs + tail scalar (25 cols), then quad reduce
__device__ __forceinline__ float dotH_(const v2f* __restrict__ w2, float w1,
                                       const v2f* __restrict__ hv2, float h24) {
    v2f a = {0.f, 0.f};
    #pragma unroll
    for (int j = 0; j < 12; ++j) a = w2[j] * hv2[j] + a;   // v_pk_fma_f32
    return red4_(fmaf(w1, h24, a.x + a.y));
}
// ctx-row dot: 8 v2f pairs (16 cols), then quad reduce
__device__ __forceinline__ float dotC_(const v2f* __restrict__ w2,
                                       const v2f* __restrict__ cv2) {
    v2f a = {0.f, 0.f};
    #pragma unroll
    for (int j = 0; j < 8; ++j) a = w2[j] * cv2[j] + a;
    return red4_(a.x + a.y);
}

__global__ __attribute__((amdgpu_flat_work_group_size(512, 512)))
__attribute__((amdgpu_waves_per_eu(2, 2)))
void rnn8(const float* __restrict__ ctx, const int* __restrict__ lens,
          const float* __restrict__ Whh, const float* __restrict__ bhh,
          const float* __restrict__ Wproj, const float* __restrict__ bproj,
          const float* __restrict__ ws, float* __restrict__ out) {

    const int tid = threadIdx.x;
    const int l   = tid & 3;          // quad lane: h-cols 25l.., ctx-cols 16l..
    const int g   = tid >> 2;         // 0..127 row-group
    const bool wl = (l == 0);

    const int* perm = (const int*)(ws + WS_PERM);
    const int e0 = perm[blockIdx.x];         // long element
    const int e1 = perm[511 - blockIdx.x];   // short element
    const int len0 = lens[e0], len1 = lens[e1];

    __shared__ __align__(16) float sh[2][112];    // h: 4 chunks of 25, stride 28
    __shared__ __align__(16) float sctx[2][64];
    __shared__ float sdot[2][672];                // gh 0..299 | xi 300..599 | proj 600..663
    __shared__ float sbh[H3], sbx[H3];

    // ---- per-pass config: slot = 128p + g ----
    const bool p2hh = (g < 44);      // pass2: slot 256..299 -> Whh, else input-path row g-44
    const bool p4a  = (g < 88);      // pass4 enc: Wc row 212+g; dec: Wd row 212+g (else Wproj)
    const bool p5a  = (g < 24);      // pass5 dec only: Wproj row 40+g

    // ---- register-resident weights: 6 passes x (12 v2f + tail) ----
    v2f   w2[6][12];
    float w1[6];
    {
        const float* r0 = Whh + g * H_ + 25 * l;
        const float* r1 = Whh + (128 + g) * H_ + 25 * l;
        #pragma unroll
        for (int j = 0; j < 12; ++j) {
            w2[0][j] = v2f{r0[2 * j], r0[2 * j + 1]};
            w2[1][j] = v2f{r1[2 * j], r1[2 * j + 1]};
        }
        w1[0] = r0[24]; w1[1] = r1[24];
        if (p2hh) {
            const float* r2 = Whh + (256 + g) * H_ + 25 * l;
            #pragma unroll
            for (int j = 0; j < 12; ++j) w2[2][j] = v2f{r2[2 * j], r2[2 * j + 1]};
            w1[2] = r2[24];
        } else {
            const float* r2 = ws + WS_WC + (g - 44) * I_ + 16 * l;
            #pragma unroll
            for (int j = 0; j < 8; ++j) w2[2][j] = v2f{r2[2 * j], r2[2 * j + 1]};
        }
        const float* r3 = ws + WS_WC + (84 + g) * I_ + 16 * l;
        #pragma unroll
        for (int j = 0; j < 8; ++j) w2[3][j] = v2f{r3[2 * j], r3[2 * j + 1]};
        if (p4a) {
            const float* r4 = ws + WS_WC + (212 + g) * I_ + 16 * l;
            #pragma unroll
            for (int j = 0; j < 8; ++j) w2[4][j] = v2f{r4[2 * j], r4[2 * j + 1]};
        }
    }

    // ---- roles (same as R7) ----
    const int ge = (tid >= 100);                 // gate threads: tid<200
    const int gi = tid - (ge ? 100 : 0);
    const int hs = 28 * (gi / 25) + (gi % 25);   // h slot in 28-stride chunks
    const int lenG = ge ? len1 : len0;
    float hreg = 0.f;

    const int oe = (tid >> 6) & 1;               // out threads: tid in [256,384)
    const int oo = tid & 63;
    float* oute = out + (size_t)(oe ? e1 : e0) * (T_ + 1) * O_;
    float bpr = 0.f;
    if (tid >= 256 && tid < 384) bpr = bproj[oo];

    const int pe = (tid >> 4) & 1;               // prefetch threads: tid in [384,416)
    const int pi = tid & 15;
    const float4* pctx = (const float4*)(ctx + (size_t)(pe ? e1 : e0) * LC_ * I_);
    const int lenP = pe ? len1 : len0;

    // ---- init ----
    if (tid < 224) ((float*)sh)[tid] = 0.f;
    if (tid < H3) { sbh[tid] = bhh[tid]; sbx[tid] = (ws + WS_BC)[tid]; }
    if (tid >= 384 && tid < 416) *(float4*)&sctx[pe][4 * pi] = pctx[pi];   // t=0
    __syncthreads();

    // ================ encoder: t = 0 .. len0-1 (len0 >= len1) ================
    for (int t = 0; t < len0; ++t) {
        float4 pf;
        const bool hp = (tid >= 384 && tid < 416) && (t + 1 < lenP);
        if (hp) pf = pctx[(t + 1) * 16 + pi];

        #pragma unroll
        for (int e = 0; e < 2; ++e) {
            if (e == 0 || t < len1) {       // block-uniform skip of finished element
                v2f hv2[12], cv2[8];
                float h24;
                #pragma unroll
                for (int q = 0; q < 6; ++q) {
                    float4 f = *(const float4*)&sh[e][28 * l + 4 * q];
                    hv2[2 * q]     = v2f{f.x, f.y};
                    hv2[2 * q + 1] = v2f{f.z, f.w};
                }
                h24 = sh[e][28 * l + 24];
                #pragma unroll
                for (int q = 0; q < 4; ++q) {
                    float4 f = *(const float4*)&sctx[e][16 * l + 4 * q];
                    cv2[2 * q]     = v2f{f.x, f.y};
                    cv2[2 * q + 1] = v2f{f.z, f.w};
                }

                float a0 = dotH_(w2[0], w1[0], hv2, h24);
                float a1 = dotH_(w2[1], w1[1], hv2, h24);
                float a2 = p2hh ? dotH_(w2[2], w1[2], hv2, h24) : dotC_(w2[2], cv2);
                float a3 = dotC_(w2[3], cv2);
                if (wl) {
                    sdot[e][g] = a0;
                    sdot[e][128 + g] = a1;
                    sdot[e][256 + g] = a2;
                    sdot[e][384 + g] = a3;
                }
                if (p4a) {
                    float a4 = dotC_(w2[4], cv2);
                    if (wl) sdot[e][512 + g] = a4;
                }
            }
        }
        __syncthreads();
        if (tid < 200 && t < lenG) {
            const float* sd = sdot[ge];
            float gr = sd[gi]       + sbh[gi];
            float gz = sd[gi + 100] + sbh[gi + 100];
            float gn = sd[gi + 200] + sbh[gi + 200];
            float xr = sd[gi + 300] + sbx[gi];
            float xz = sd[gi + 400] + sbx[gi + 100];
            float xn = sd[gi + 500] + sbx[gi + 200];
            float r = sigm_(xr + gr);
            float z = sigm_(xz + gz);
            float n = tanh_(xn + r * gn);
            hreg = (1.f - z) * n + z * hreg;
            sh[ge][hs] = hreg;
        }
        if (hp) *(float4*)&sctx[pe][4 * pi] = pf;
        __syncthreads();
    }

    // ---- switch input-path weights to decoder: Wd (+Wproj rows), bc -> bd ----
    {
        if (!p2hh) {
            const float* r2 = ws + WS_WD + (g - 44) * H_ + 25 * l;
            #pragma unroll
            for (int j = 0; j < 12; ++j) w2[2][j] = v2f{r2[2 * j], r2[2 * j + 1]};
            w1[2] = r2[24];
        }
        const float* r3 = ws + WS_WD + (84 + g) * H_ + 25 * l;
        #pragma unroll
        for (int j = 0; j < 12; ++j) w2[3][j] = v2f{r3[2 * j], r3[2 * j + 1]};
        w1[3] = r3[24];
        const float* r4 = p4a ? (ws + WS_WD + (212 + g) * H_ + 25 * l)
                              : (Wproj + (g - 88) * H_ + 25 * l);
        #pragma unroll
        for (int j = 0; j < 12; ++j) w2[4][j] = v2f{r4[2 * j], r4[2 * j + 1]};
        w1[4] = r4[24];
        if (p5a) {
            const float* r5 = Wproj + (40 + g) * H_ + 25 * l;
            #pragma unroll
            for (int j = 0; j < 12; ++j) w2[5][j] = v2f{r5[2 * j], r5[2 * j + 1]};
            w1[5] = r5[24];
        }
    }
    if (tid < H3) sbx[tid] = (ws + WS_BD)[tid];
    // safe: sbx next read only after the decoder's first __syncthreads()

    // ================ decoder: outputs t = 0..256 ================
    for (int t = 0; t <= T_; ++t) {
        #pragma unroll
        for (int e = 0; e < 2; ++e) {
            v2f hv2[12];
            float h24;
            #pragma unroll
            for (int q = 0; q < 6; ++q) {
                float4 f = *(const float4*)&sh[e][28 * l + 4 * q];
                hv2[2 * q]     = v2f{f.x, f.y};
                hv2[2 * q + 1] = v2f{f.z, f.w};
            }
            h24 = sh[e][28 * l + 24];

            float a0 = dotH_(w2[0], w1[0], hv2, h24);
            float a1 = dotH_(w2[1], w1[1], hv2, h24);
            float a2 = dotH_(w2[2], w1[2], hv2, h24);
            float a3 = dotH_(w2[3], w1[3], hv2, h24);
            float a4 = dotH_(w2[4], w1[4], hv2, h24);
            if (wl) {
                sdot[e][g] = a0;
                sdot[e][128 + g] = a1;
                sdot[e][256 + g] = a2;
                sdot[e][384 + g] = a3;
                sdot[e][512 + g] = a4;
            }
            if (p5a) {
                float a5 = dotH_(w2[5], w1[5], hv2, h24);
                if (wl) sdot[e][640 + g] = a5;
            }
        }
        __syncthreads();
        if (tid >= 256 && tid < 384) {
            oute[t * O_ + oo] = sdot[oe][600 + oo] + bpr;
        }
        if (t == T_) break;   // uniform
        if (tid < 200) {
            const float* sd = sdot[ge];
            float gr = sd[gi]       + sbh[gi];
            float gz = sd[gi + 100] + sbh[gi + 100];
            float gn = sd[gi + 200] + sbh[gi + 200];
            float xr = sd[gi + 300] + sbx[gi];
            float xz = sd[gi + 400] + sbx[gi + 100];
            float xn = sd[gi + 500] + sbx[gi + 200];
            float r = sigm_(xr + gr);
            float z = sigm_(xz + gz);
            float n = tanh_(xn + r * gn);
            hreg = (1.f - z) * n + z * hreg;
            sh[ge][hs] = hreg;
        }
        __syncthreads();
    }
}

extern "C" void kernel_launch(void* const* d_in, const int* in_sizes, int n_in,
                              void* d_out, int out_size, void* d_ws, size_t ws_size,
                              hipStream_t stream) {
    (void)in_sizes; (void)n_in; (void)out_size; (void)ws_size;
    const float* ctx  = (const float*)d_in[0];
    const int*   lens = (const int*)d_in[1];
    // d_in[2] = t_steps (256, hardcoded)
    const float* Wemb = (const float*)d_in[3];
    const float* bemb = (const float*)d_in[4];
    const float* Wih  = (const float*)d_in[5];
    const float* bih  = (const float*)d_in[6];
    const float* Whh  = (const float*)d_in[7];
    const float* bhh  = (const float*)d_in[8];
    const float* Wpr  = (const float*)d_in[9];
    const float* bpr  = (const float*)d_in[10];
    float* ws  = (float*)d_ws;
    float* out = (float*)d_out;

    prep1<<<H3, 64, 0, stream>>>(Wih, bih, Wemb, bemb, ws);
    prep2<<<H3, 128, 0, stream>>>(Wpr, bpr, ws);
    sortk<<<1, 512, 0, stream>>>(lens, (int*)(ws + WS_PERM));
    rnn8<<<256, 512, 0, stream>>>(ctx, lens, Whh, bhh, Wpr, bpr, ws, out);
}